// Round 3
// baseline (413.344 us; speedup 1.0000x reference)
//
#include <hip/hip_runtime.h>
#include <hip/hip_bf16.h>

#define B_ROWS 4096
#define D_K    256
#define Q_ROWS 65536
#define HALF   2048

typedef __bf16 bf16x8 __attribute__((ext_vector_type(8)));
typedef float  f32x4  __attribute__((ext_vector_type(4)));
typedef const __attribute__((address_space(1))) void* gptr1;
typedef __attribute__((address_space(3))) void* lptr3;

__device__ __forceinline__ unsigned int f32_ordered(float f) {
    unsigned int u = __float_as_uint(f);
    return (u & 0x80000000u) ? ~u : (u | 0x80000000u);
}

__device__ __forceinline__ unsigned short f2bf_rn(float f) {
    unsigned int u = __float_as_uint(f);
    u += 0x7FFFu + ((u >> 16) & 1u);
    return (unsigned short)(u >> 16);
}

// ---------- f32 -> bf16 (RNE), 4 elems/thread ----------
__global__ __launch_bounds__(256) void cvt_bf16_kernel(const float* __restrict__ in,
                                                       unsigned short* __restrict__ out,
                                                       int n4) {
    int i = blockIdx.x * 256 + threadIdx.x;
    if (i >= n4) return;
    float4 v = ((const float4*)in)[i];
    ushort4 o;
    o.x = f2bf_rn(v.x); o.y = f2bf_rn(v.y); o.z = f2bf_rn(v.z); o.w = f2bf_rn(v.w);
    ((ushort4*)out)[i] = o;
}

// ---------- zero argmax array ----------
__global__ __launch_bounds__(256) void init_amax_kernel(unsigned long long* amax) {
    int i = blockIdx.x * 256 + threadIdx.x;
    if (i < B_ROWS) amax[i] = 0ull;  // ordered-float 0 == below every real value
}

// ---------- fused sim GEMM + row argmax ----------
// Double-buffered async staging, ONE barrier per K-iter: prefetch for iter i+1
// issued immediately after the barrier, before compute on iter i. The
// barrier's vmcnt(0) drain then waits on loads issued a full compute-phase
// earlier (staging misses go to HBM here, ~900 cyc).
#define BM 128
#define BN 128
#define BK 32
#define NCHUNK 8
__global__ __launch_bounds__(256) void sim_argmax_kernel(const unsigned short* __restrict__ A,
                                                         const unsigned short* __restrict__ Bq,
                                                         unsigned long long* __restrict__ amax) {
    __shared__ unsigned short As[2][BM * BK];   // 2 x 8 KB (NO padding: global_load_lds)
    __shared__ unsigned short Bs[2][BN * BK];   // 2 x 8 KB

    const int tid  = threadIdx.x;
    const int wave = tid >> 6;
    const int lane = tid & 63;
    const int l15  = lane & 15;
    const int quad = lane >> 4;
    const int blk_m = blockIdx.x * BM;              // x fastest: m-blocks share the B n-tile via L2/LLC
    const int nbase = blockIdx.y * (BN * NCHUNK);
    const int wave_m = (wave >> 1) * 64;
    const int wave_n = (wave & 1) * 64;

    // staging: chunk q = wave*2+j covers LDS bytes [q*1024, q*1024+1024); lane i -> byte q*1024+i*16
    const int srow  = lane >> 2;        // 0..15 within chunk
    const int skoff = (lane & 3) * 8;   // element offset in K

    float bestv[4][4];
    int   bestc[4][4];
#pragma unroll
    for (int mi = 0; mi < 4; mi++)
#pragma unroll
        for (int reg = 0; reg < 4; reg++) { bestv[mi][reg] = -1e30f; bestc[mi][reg] = 0; }

    f32x4 acc[4][4];
#pragma unroll
    for (int i = 0; i < 4; i++)
#pragma unroll
        for (int j = 0; j < 4; j++) acc[i][j] = (f32x4){0.f, 0.f, 0.f, 0.f};

    const int q0 = wave * 2, q1 = wave * 2 + 1;
    const int row0 = q0 * 16 + srow, row1 = q1 * 16 + srow;

    // prologue: issue tile 0 (nc=0, kb=0) into buf 0
    {
        const unsigned short* ga0 = A  + (size_t)(blk_m + row0) * D_K + skoff;
        const unsigned short* gb0 = Bq + (size_t)(nbase + row0) * D_K + skoff;
        const unsigned short* ga1 = A  + (size_t)(blk_m + row1) * D_K + skoff;
        const unsigned short* gb1 = Bq + (size_t)(nbase + row1) * D_K + skoff;
        __builtin_amdgcn_global_load_lds((gptr1)ga0, (lptr3)&As[0][q0 * 16 * BK], 16, 0, 0);
        __builtin_amdgcn_global_load_lds((gptr1)gb0, (lptr3)&Bs[0][q0 * 16 * BK], 16, 0, 0);
        __builtin_amdgcn_global_load_lds((gptr1)ga1, (lptr3)&As[0][q1 * 16 * BK], 16, 0, 0);
        __builtin_amdgcn_global_load_lds((gptr1)gb1, (lptr3)&Bs[0][q1 * 16 * BK], 16, 0, 0);
    }

    int cur = 0;
#pragma unroll 1
    for (int it = 0; it < NCHUNK * 8; ++it) {
        __syncthreads();   // drains vmcnt(0): tile `it` (issued last iter) is ready; buf cur^1 free

        const int nxt = it + 1;
        if (nxt < NCHUNK * 8) {   // issue prefetch of tile it+1 into the other buffer
            const int kbn = (nxt & 7) * BK;
            const int bnn = nbase + (nxt >> 3) * BN;
            const unsigned short* ga0 = A  + (size_t)(blk_m + row0) * D_K + kbn + skoff;
            const unsigned short* gb0 = Bq + (size_t)(bnn   + row0) * D_K + kbn + skoff;
            const unsigned short* ga1 = A  + (size_t)(blk_m + row1) * D_K + kbn + skoff;
            const unsigned short* gb1 = Bq + (size_t)(bnn   + row1) * D_K + kbn + skoff;
            __builtin_amdgcn_global_load_lds((gptr1)ga0, (lptr3)&As[cur ^ 1][q0 * 16 * BK], 16, 0, 0);
            __builtin_amdgcn_global_load_lds((gptr1)gb0, (lptr3)&Bs[cur ^ 1][q0 * 16 * BK], 16, 0, 0);
            __builtin_amdgcn_global_load_lds((gptr1)ga1, (lptr3)&As[cur ^ 1][q1 * 16 * BK], 16, 0, 0);
            __builtin_amdgcn_global_load_lds((gptr1)gb1, (lptr3)&Bs[cur ^ 1][q1 * 16 * BK], 16, 0, 0);
        }

        bf16x8 a_frag[4], b_frag[4];
#pragma unroll
        for (int mi = 0; mi < 4; mi++)
            a_frag[mi] = *(const bf16x8*)&As[cur][(wave_m + mi * 16 + l15) * BK + quad * 8];
#pragma unroll
        for (int ni = 0; ni < 4; ni++)
            b_frag[ni] = *(const bf16x8*)&Bs[cur][(wave_n + ni * 16 + l15) * BK + quad * 8];
#pragma unroll
        for (int mi = 0; mi < 4; mi++)
#pragma unroll
            for (int ni = 0; ni < 4; ni++)
                acc[mi][ni] = __builtin_amdgcn_mfma_f32_16x16x32_bf16(a_frag[mi], b_frag[ni],
                                                                      acc[mi][ni], 0, 0, 0);

        if ((it & 7) == 7) {
            // nc = it>>3 complete: fold into running best, reset acc
            const int col0 = nbase + (it >> 3) * BN + wave_n + l15;
#pragma unroll
            for (int mi = 0; mi < 4; mi++) {
#pragma unroll
                for (int reg = 0; reg < 4; reg++) {
#pragma unroll
                    for (int ni = 0; ni < 4; ni++) {
                        float v = acc[mi][ni][reg];
                        int   c = col0 + ni * 16;
                        if (v > bestv[mi][reg]) { bestv[mi][reg] = v; bestc[mi][reg] = c; }
                    }
                    acc[mi][0][reg] = 0.f; acc[mi][1][reg] = 0.f;
                    acc[mi][2][reg] = 0.f; acc[mi][3][reg] = 0.f;
                }
            }
        }
        cur ^= 1;
    }

    // Epilogue (once per block): pack, 16-lane reduce, one atomic per slot
#pragma unroll
    for (int mi = 0; mi < 4; mi++) {
#pragma unroll
        for (int reg = 0; reg < 4; reg++) {
            unsigned long long key =
                ((unsigned long long)f32_ordered(bestv[mi][reg]) << 32) |
                (unsigned long long)(0xFFFFFFFFu - (unsigned)bestc[mi][reg]);   // ~col: ties -> smaller col
#pragma unroll
            for (int m = 1; m < 16; m <<= 1) {
                unsigned long long o = __shfl_xor(key, m, 16);
                if (o > key) key = o;
            }
            if (l15 == mi * 4 + reg) {  // spread the 16 atomics across the 16 lanes of the group
                int row = blk_m + wave_m + mi * 16 + quad * 4 + reg;
                atomicMax(&amax[row], key);
            }
        }
    }
}

// ---------- gather nearest rows (bf16) ----------
__global__ __launch_bounds__(64) void gather_kernel(const unsigned long long* __restrict__ amax,
                                                    const unsigned short* __restrict__ queue_bf,
                                                    unsigned short* __restrict__ nearest_bf) {
    int row = blockIdx.x;
    unsigned idx = 0xFFFFFFFFu - (unsigned)(amax[row] & 0xFFFFFFFFull);
    const ushort4* src = (const ushort4*)(queue_bf + (size_t)idx * D_K);
    ushort4* dst = (ushort4*)(nearest_bf + (size_t)row * D_K);
    dst[threadIdx.x] = src[threadIdx.x];   // 64 lanes x 8B = 512B = full row
}

// ---------- logits + online logsumexp - diag ----------
// one block (8 waves, 512 thr) per 16 rows; waves split the 128 column-tiles
// 16 each, partial (m,l,diag) merged through LDS.
__global__ __launch_bounds__(512) void logits_ce_kernel(const unsigned short* __restrict__ nearest_bf,
                                                        const unsigned short* __restrict__ preds_bf,
                                                        float* __restrict__ row_loss) {
    const int gw   = blockIdx.x;        // 0..255 (16-row group)
    const int tid  = threadIdx.x;
    const int wave = tid >> 6;          // 0..7
    const int lane = tid & 63;
    const int l15  = lane & 15;
    const int quad = lane >> 4;
    const int h    = gw >> 7;           // 0: ab, 1: ba
    const int rowbase = gw * 16;        // global row base
    const unsigned short* Bbase = preds_bf + (size_t)((1 - h) * HALF) * D_K;

    __shared__ float sm[8][16], sl[8][16], sd[8][16];

    bf16x8 a[8];
#pragma unroll
    for (int kc = 0; kc < 8; kc++)
        a[kc] = *(const bf16x8*)&nearest_bf[(size_t)(rowbase + l15) * D_K + kc * 32 + quad * 8];

    float m_run[4], l_run[4], diag[4];
#pragma unroll
    for (int r = 0; r < 4; r++) { m_run[r] = -1e30f; l_run[r] = 0.f; diag[r] = -1e30f; }

    const int tdiag = gw & 127;
    for (int tt = 0; tt < 16; tt++) {
        const int t = wave * 16 + tt;
        f32x4 acc = (f32x4){0.f, 0.f, 0.f, 0.f};
#pragma unroll
        for (int kc = 0; kc < 8; kc++) {
            bf16x8 b = *(const bf16x8*)&Bbase[(size_t)(t * 16 + l15) * D_K + kc * 32 + quad * 8];
            acc = __builtin_amdgcn_mfma_f32_16x16x32_bf16(a[kc], b, acc, 0, 0, 0);
        }
#pragma unroll
        for (int reg = 0; reg < 4; reg++) {
            float v = acc[reg] * 10.0f;              // 1/TEMPERATURE
            int mrow = quad * 4 + reg;
            if (t == tdiag && l15 == mrow) diag[reg] = v;
            float nm = fmaxf(m_run[reg], v);
            l_run[reg] = l_run[reg] * __expf(m_run[reg] - nm) + __expf(v - nm);
            m_run[reg] = nm;
        }
    }
    // 16-lane merge within the wave
#pragma unroll
    for (int reg = 0; reg < 4; reg++) {
#pragma unroll
        for (int m = 1; m < 16; m <<= 1) {
            float om = __shfl_xor(m_run[reg], m, 16);
            float ol = __shfl_xor(l_run[reg], m, 16);
            float od = __shfl_xor(diag[reg], m, 16);
            float nm = fmaxf(m_run[reg], om);
            l_run[reg] = l_run[reg] * __expf(m_run[reg] - nm) + ol * __expf(om - nm);
            m_run[reg] = nm;
            diag[reg] = fmaxf(diag[reg], od);
        }
        if (l15 == 0) {
            sm[wave][quad * 4 + reg] = m_run[reg];
            sl[wave][quad * 4 + reg] = l_run[reg];
            sd[wave][quad * 4 + reg] = diag[reg];
        }
    }
    __syncthreads();
    // cross-wave merge: thread r (0..15) owns row rowbase+r
    if (tid < 16) {
        float M = -1e30f, L = 0.f, Dg = -1e30f;
#pragma unroll
        for (int w = 0; w < 8; w++) {
            float mw = sm[w][tid], lw = sl[w][tid], dw = sd[w][tid];
            float nM = fmaxf(M, mw);
            L = L * __expf(M - nM) + lw * __expf(mw - nM);
            M = nM;
            Dg = fmaxf(Dg, dw);
        }
        row_loss[rowbase + tid] = (M + __logf(L)) - Dg;
    }
}

// ---------- final scalar reduce ----------
__global__ __launch_bounds__(256) void reduce_kernel(const float* __restrict__ row_loss,
                                                     float* __restrict__ out) {
    __shared__ float sdata[4];
    float s = 0.f;
    for (int i = threadIdx.x; i < B_ROWS; i += 256) s += row_loss[i];
#pragma unroll
    for (int m = 1; m < 64; m <<= 1) s += __shfl_xor(s, m, 64);
    if ((threadIdx.x & 63) == 0) sdata[threadIdx.x >> 6] = s;
    __syncthreads();
    if (threadIdx.x == 0)
        out[0] = (sdata[0] + sdata[1] + sdata[2] + sdata[3]) / (float)B_ROWS;
}

extern "C" void kernel_launch(void* const* d_in, const int* in_sizes, int n_in,
                              void* d_out, int out_size, void* d_ws, size_t ws_size,
                              hipStream_t stream) {
    const float* emb   = (const float*)d_in[0];
    const float* preds = (const float*)d_in[1];
    const float* queue = (const float*)d_in[2];

    char* w = (char*)d_ws;
    unsigned long long* amax   = (unsigned long long*)w;            // 32 KB
    float*          row_loss   = (float*)(w + (32 << 10));          // 16 KB
    unsigned short* emb_bf     = (unsigned short*)(w + (64 << 10));         // 2 MB
    unsigned short* preds_bf   = (unsigned short*)(w + (64 << 10) + (2u << 20));      // 2 MB
    unsigned short* queue_bf   = (unsigned short*)(w + (64 << 10) + (4u << 20));      // 32 MB
    unsigned short* nearest_bf = (unsigned short*)(w + (64 << 10) + (36u << 20));     // 2 MB

    cvt_bf16_kernel<<<dim3((B_ROWS * D_K / 4) / 256), 256, 0, stream>>>(emb, emb_bf, B_ROWS * D_K / 4);
    cvt_bf16_kernel<<<dim3((B_ROWS * D_K / 4) / 256), 256, 0, stream>>>(preds, preds_bf, B_ROWS * D_K / 4);
    cvt_bf16_kernel<<<dim3((Q_ROWS * D_K / 4) / 256), 256, 0, stream>>>(queue, queue_bf, Q_ROWS * D_K / 4);
    init_amax_kernel<<<dim3(B_ROWS / 256), 256, 0, stream>>>(amax);
    sim_argmax_kernel<<<dim3(B_ROWS / BM, Q_ROWS / (BN * NCHUNK)), 256, 0, stream>>>(emb_bf, queue_bf, amax);
    gather_kernel<<<dim3(B_ROWS), 64, 0, stream>>>(amax, queue_bf, nearest_bf);
    logits_ce_kernel<<<dim3(B_ROWS / 16), 512, 0, stream>>>(nearest_bf, preds_bf, row_loss);
    reduce_kernel<<<dim3(1), 256, 0, stream>>>(row_loss, (float*)d_out);
}

// Round 4
// 338.038 us; speedup vs baseline: 1.2228x; 1.2228x over previous
//
#include <hip/hip_runtime.h>
#include <hip/hip_bf16.h>

#define B_ROWS 4096
#define D_K    256
#define Q_ROWS 65536
#define HALF   2048

typedef __bf16 bf16x8 __attribute__((ext_vector_type(8)));
typedef float  f32x4  __attribute__((ext_vector_type(4)));
typedef const __attribute__((address_space(1))) void* gptr1;
typedef __attribute__((address_space(3))) void* lptr3;

__device__ __forceinline__ unsigned int f32_ordered(float f) {
    unsigned int u = __float_as_uint(f);
    return (u & 0x80000000u) ? ~u : (u | 0x80000000u);
}

__device__ __forceinline__ unsigned short f2bf_rn(float f) {
    unsigned int u = __float_as_uint(f);
    u += 0x7FFFu + ((u >> 16) & 1u);
    return (unsigned short)(u >> 16);
}

// ---------- f32 -> bf16 (RNE), 4 elems/thread ----------
__global__ __launch_bounds__(256) void cvt_bf16_kernel(const float* __restrict__ in,
                                                       unsigned short* __restrict__ out,
                                                       int n4) {
    int i = blockIdx.x * 256 + threadIdx.x;
    if (i >= n4) return;
    float4 v = ((const float4*)in)[i];
    ushort4 o;
    o.x = f2bf_rn(v.x); o.y = f2bf_rn(v.y); o.z = f2bf_rn(v.z); o.w = f2bf_rn(v.w);
    ((ushort4*)out)[i] = o;
}

// ---------- zero argmax array ----------
__global__ __launch_bounds__(256) void init_amax_kernel(unsigned long long* amax) {
    int i = blockIdx.x * 256 + threadIdx.x;
    if (i < B_ROWS) amax[i] = 0ull;  // ordered-float 0 == below every real value
}

// ---------- fused sim GEMM + row argmax ----------
// R2 body (2-barrier m97 K-loop, register-running argmax over NCHUNK n-tiles).
// Grid is XCD-swizzled 1-D: bid%8 selects the n-group stripe so each XCD's
// co-resident blocks share a ~2MB queue slice (fits its private 4MB L2) ->
// staging loads hit L2 instead of HBM.
#define BM 128
#define BN 128
#define BK 32
#define NCHUNK 8
__global__ __launch_bounds__(256) void sim_argmax_kernel(const unsigned short* __restrict__ A,
                                                         const unsigned short* __restrict__ Bq,
                                                         unsigned long long* __restrict__ amax) {
    __shared__ unsigned short As[BM * BK];   // row-major, K contiguous (NO padding: global_load_lds)
    __shared__ unsigned short Bs[BN * BK];

    const int tid  = threadIdx.x;
    const int wave = tid >> 6;
    const int lane = tid & 63;
    const int l15  = lane & 15;
    const int quad = lane >> 4;

    // XCD-aware swizzle: block i -> XCD i%8 (dispatch heuristic). Each XCD
    // works n-groups {x, 8+x, 16+x, 24+x} concurrently across all 32 m-blocks.
    const int bid  = blockIdx.x;
    const int xcd  = bid & 7;
    const int j    = bid >> 3;
    const int blk_m = (j & 31) * BM;
    const int ngrp  = (j >> 5) * 8 + xcd;
    const int nbase = ngrp * (BN * NCHUNK);

    const int wave_m = (wave >> 1) * 64;
    const int wave_n = (wave & 1) * 64;

    // staging: chunk q = wave*2+j covers LDS bytes [q*1024, q*1024+1024); lane i -> byte q*1024+i*16
    const int srow  = lane >> 2;        // 0..15 within chunk
    const int skoff = (lane & 3) * 8;   // element offset in K

    float bestv[4][4];
    int   bestc[4][4];
#pragma unroll
    for (int mi = 0; mi < 4; mi++)
#pragma unroll
        for (int reg = 0; reg < 4; reg++) { bestv[mi][reg] = -1e30f; bestc[mi][reg] = 0; }

#pragma unroll 1
    for (int nc = 0; nc < NCHUNK; nc++) {
        const int blk_n = nbase + nc * BN;

        f32x4 acc[4][4];
#pragma unroll
        for (int i = 0; i < 4; i++)
#pragma unroll
            for (int jj = 0; jj < 4; jj++) acc[i][jj] = (f32x4){0.f, 0.f, 0.f, 0.f};

        for (int kb = 0; kb < D_K; kb += BK) {
#pragma unroll
            for (int jj = 0; jj < 2; jj++) {
                int q = wave * 2 + jj;
                int row = q * 16 + srow;
                const unsigned short* ga = A  + (size_t)(blk_m + row) * D_K + kb + skoff;
                const unsigned short* gb = Bq + (size_t)(blk_n + row) * D_K + kb + skoff;
                __builtin_amdgcn_global_load_lds((gptr1)ga, (lptr3)&As[q * 16 * BK], 16, 0, 0);
                __builtin_amdgcn_global_load_lds((gptr1)gb, (lptr3)&Bs[q * 16 * BK], 16, 0, 0);
            }
            __syncthreads();

            bf16x8 a_frag[4], b_frag[4];
#pragma unroll
            for (int mi = 0; mi < 4; mi++)
                a_frag[mi] = *(const bf16x8*)&As[(wave_m + mi * 16 + l15) * BK + quad * 8];
#pragma unroll
            for (int ni = 0; ni < 4; ni++)
                b_frag[ni] = *(const bf16x8*)&Bs[(wave_n + ni * 16 + l15) * BK + quad * 8];
#pragma unroll
            for (int mi = 0; mi < 4; mi++)
#pragma unroll
                for (int ni = 0; ni < 4; ni++)
                    acc[mi][ni] = __builtin_amdgcn_mfma_f32_16x16x32_bf16(a_frag[mi], b_frag[ni],
                                                                          acc[mi][ni], 0, 0, 0);
            __syncthreads();
        }

        // fold this n-chunk into the running per-slot best (registers only)
        const int col0 = blk_n + wave_n + l15;
#pragma unroll
        for (int mi = 0; mi < 4; mi++) {
#pragma unroll
            for (int reg = 0; reg < 4; reg++) {
#pragma unroll
                for (int ni = 0; ni < 4; ni++) {
                    float v = acc[mi][ni][reg];
                    int   c = col0 + ni * 16;
                    if (v > bestv[mi][reg]) { bestv[mi][reg] = v; bestc[mi][reg] = c; }
                }
            }
        }
    }

    // Epilogue (once per block): pack, 16-lane reduce, one atomic per slot
#pragma unroll
    for (int mi = 0; mi < 4; mi++) {
#pragma unroll
        for (int reg = 0; reg < 4; reg++) {
            unsigned long long key =
                ((unsigned long long)f32_ordered(bestv[mi][reg]) << 32) |
                (unsigned long long)(0xFFFFFFFFu - (unsigned)bestc[mi][reg]);   // ~col: ties -> smaller col
#pragma unroll
            for (int m = 1; m < 16; m <<= 1) {
                unsigned long long o = __shfl_xor(key, m, 16);
                if (o > key) key = o;
            }
            if (l15 == mi * 4 + reg) {  // spread the 16 atomics across the 16 lanes of the group
                int row = blk_m + wave_m + mi * 16 + quad * 4 + reg;
                atomicMax(&amax[row], key);
            }
        }
    }
}

// ---------- gather nearest rows (bf16) ----------
__global__ __launch_bounds__(64) void gather_kernel(const unsigned long long* __restrict__ amax,
                                                    const unsigned short* __restrict__ queue_bf,
                                                    unsigned short* __restrict__ nearest_bf) {
    int row = blockIdx.x;
    unsigned idx = 0xFFFFFFFFu - (unsigned)(amax[row] & 0xFFFFFFFFull);
    const ushort4* src = (const ushort4*)(queue_bf + (size_t)idx * D_K);
    ushort4* dst = (ushort4*)(nearest_bf + (size_t)row * D_K);
    dst[threadIdx.x] = src[threadIdx.x];   // 64 lanes x 8B = 512B = full row
}

// ---------- logits + online logsumexp - diag ----------
// one block (8 waves, 512 thr) per 16 rows; waves split the 128 column-tiles
// 16 each, partial (m,l,diag) merged through LDS.
__global__ __launch_bounds__(512) void logits_ce_kernel(const unsigned short* __restrict__ nearest_bf,
                                                        const unsigned short* __restrict__ preds_bf,
                                                        float* __restrict__ row_loss) {
    const int gw   = blockIdx.x;        // 0..255 (16-row group)
    const int tid  = threadIdx.x;
    const int wave = tid >> 6;          // 0..7
    const int lane = tid & 63;
    const int l15  = lane & 15;
    const int quad = lane >> 4;
    const int h    = gw >> 7;           // 0: ab, 1: ba
    const int rowbase = gw * 16;        // global row base
    const unsigned short* Bbase = preds_bf + (size_t)((1 - h) * HALF) * D_K;

    __shared__ float sm[8][16], sl[8][16], sd[8][16];

    bf16x8 a[8];
#pragma unroll
    for (int kc = 0; kc < 8; kc++)
        a[kc] = *(const bf16x8*)&nearest_bf[(size_t)(rowbase + l15) * D_K + kc * 32 + quad * 8];

    float m_run[4], l_run[4], diag[4];
#pragma unroll
    for (int r = 0; r < 4; r++) { m_run[r] = -1e30f; l_run[r] = 0.f; diag[r] = -1e30f; }

    const int tdiag = gw & 127;
    for (int tt = 0; tt < 16; tt++) {
        const int t = wave * 16 + tt;
        f32x4 acc = (f32x4){0.f, 0.f, 0.f, 0.f};
#pragma unroll
        for (int kc = 0; kc < 8; kc++) {
            bf16x8 b = *(const bf16x8*)&Bbase[(size_t)(t * 16 + l15) * D_K + kc * 32 + quad * 8];
            acc = __builtin_amdgcn_mfma_f32_16x16x32_bf16(a[kc], b, acc, 0, 0, 0);
        }
#pragma unroll
        for (int reg = 0; reg < 4; reg++) {
            float v = acc[reg] * 10.0f;              // 1/TEMPERATURE
            int mrow = quad * 4 + reg;
            if (t == tdiag && l15 == mrow) diag[reg] = v;
            float nm = fmaxf(m_run[reg], v);
            l_run[reg] = l_run[reg] * __expf(m_run[reg] - nm) + __expf(v - nm);
            m_run[reg] = nm;
        }
    }
    // 16-lane merge within the wave
#pragma unroll
    for (int reg = 0; reg < 4; reg++) {
#pragma unroll
        for (int m = 1; m < 16; m <<= 1) {
            float om = __shfl_xor(m_run[reg], m, 16);
            float ol = __shfl_xor(l_run[reg], m, 16);
            float od = __shfl_xor(diag[reg], m, 16);
            float nm = fmaxf(m_run[reg], om);
            l_run[reg] = l_run[reg] * __expf(m_run[reg] - nm) + ol * __expf(om - nm);
            m_run[reg] = nm;
            diag[reg] = fmaxf(diag[reg], od);
        }
        if (l15 == 0) {
            sm[wave][quad * 4 + reg] = m_run[reg];
            sl[wave][quad * 4 + reg] = l_run[reg];
            sd[wave][quad * 4 + reg] = diag[reg];
        }
    }
    __syncthreads();
    // cross-wave merge: thread r (0..15) owns row rowbase+r
    if (tid < 16) {
        float M = -1e30f, L = 0.f, Dg = -1e30f;
#pragma unroll
        for (int w = 0; w < 8; w++) {
            float mw = sm[w][tid], lw = sl[w][tid], dw = sd[w][tid];
            float nM = fmaxf(M, mw);
            L = L * __expf(M - nM) + lw * __expf(mw - nM);
            M = nM;
            Dg = fmaxf(Dg, dw);
        }
        row_loss[rowbase + tid] = (M + __logf(L)) - Dg;
    }
}

// ---------- final scalar reduce ----------
__global__ __launch_bounds__(256) void reduce_kernel(const float* __restrict__ row_loss,
                                                     float* __restrict__ out) {
    __shared__ float sdata[4];
    float s = 0.f;
    for (int i = threadIdx.x; i < B_ROWS; i += 256) s += row_loss[i];
#pragma unroll
    for (int m = 1; m < 64; m <<= 1) s += __shfl_xor(s, m, 64);
    if ((threadIdx.x & 63) == 0) sdata[threadIdx.x >> 6] = s;
    __syncthreads();
    if (threadIdx.x == 0)
        out[0] = (sdata[0] + sdata[1] + sdata[2] + sdata[3]) / (float)B_ROWS;
}

extern "C" void kernel_launch(void* const* d_in, const int* in_sizes, int n_in,
                              void* d_out, int out_size, void* d_ws, size_t ws_size,
                              hipStream_t stream) {
    const float* emb   = (const float*)d_in[0];
    const float* preds = (const float*)d_in[1];
    const float* queue = (const float*)d_in[2];

    char* w = (char*)d_ws;
    unsigned long long* amax   = (unsigned long long*)w;            // 32 KB
    float*          row_loss   = (float*)(w + (32 << 10));          // 16 KB
    unsigned short* emb_bf     = (unsigned short*)(w + (64 << 10));         // 2 MB
    unsigned short* preds_bf   = (unsigned short*)(w + (64 << 10) + (2u << 20));      // 2 MB
    unsigned short* queue_bf   = (unsigned short*)(w + (64 << 10) + (4u << 20));      // 32 MB
    unsigned short* nearest_bf = (unsigned short*)(w + (64 << 10) + (36u << 20));     // 2 MB

    cvt_bf16_kernel<<<dim3((B_ROWS * D_K / 4) / 256), 256, 0, stream>>>(emb, emb_bf, B_ROWS * D_K / 4);
    cvt_bf16_kernel<<<dim3((B_ROWS * D_K / 4) / 256), 256, 0, stream>>>(preds, preds_bf, B_ROWS * D_K / 4);
    cvt_bf16_kernel<<<dim3((Q_ROWS * D_K / 4) / 256), 256, 0, stream>>>(queue, queue_bf, Q_ROWS * D_K / 4);
    init_amax_kernel<<<dim3(B_ROWS / 256), 256, 0, stream>>>(amax);
    sim_argmax_kernel<<<dim3((B_ROWS / BM) * (Q_ROWS / (BN * NCHUNK))), 256, 0, stream>>>(emb_bf, queue_bf, amax);
    gather_kernel<<<dim3(B_ROWS), 64, 0, stream>>>(amax, queue_bf, nearest_bf);
    logits_ce_kernel<<<dim3(B_ROWS / 16), 512, 0, stream>>>(nearest_bf, preds_bf, row_loss);
    reduce_kernel<<<dim3(1), 256, 0, stream>>>(row_loss, (float*)d_out);
}

// Round 5
// 310.344 us; speedup vs baseline: 1.3319x; 1.0892x over previous
//
#include <hip/hip_runtime.h>
#include <hip/hip_bf16.h>

#define B_ROWS 4096
#define D_K    256
#define Q_ROWS 65536
#define HALF   2048

typedef __bf16 bf16x8 __attribute__((ext_vector_type(8)));
typedef float  f32x4  __attribute__((ext_vector_type(4)));
typedef const __attribute__((address_space(1))) void* gptr1;
typedef __attribute__((address_space(3))) void* lptr3;

__device__ __forceinline__ unsigned int f32_ordered(float f) {
    unsigned int u = __float_as_uint(f);
    return (u & 0x80000000u) ? ~u : (u | 0x80000000u);
}

__device__ __forceinline__ unsigned short f2bf_rn(float f) {
    unsigned int u = __float_as_uint(f);
    u += 0x7FFFu + ((u >> 16) & 1u);
    return (unsigned short)(u >> 16);
}

// ---------- fused prep: f32->bf16 for all 3 inputs + zero amax + zero out ----------
#define EMB4  (B_ROWS * D_K / 4)          // 262144
#define PRED4 (B_ROWS * D_K / 4)          // 262144
#define QUE4  (Q_ROWS * D_K / 4)          // 4194304
__global__ __launch_bounds__(256) void prep_kernel(const float* __restrict__ emb,
                                                   const float* __restrict__ preds,
                                                   const float* __restrict__ queue,
                                                   unsigned short* __restrict__ emb_bf,
                                                   unsigned short* __restrict__ preds_bf,
                                                   unsigned short* __restrict__ queue_bf,
                                                   unsigned long long* __restrict__ amax,
                                                   float* __restrict__ out) {
    int i = blockIdx.x * 256 + threadIdx.x;
    const float* src;
    unsigned short* dst;
    int off;
    if (i < EMB4)              { src = emb;   dst = emb_bf;   off = i; }
    else if (i < EMB4 + PRED4) { src = preds; dst = preds_bf; off = i - EMB4; }
    else                       { src = queue; dst = queue_bf; off = i - EMB4 - PRED4; }
    float4 v = ((const float4*)src)[off];
    ushort4 o;
    o.x = f2bf_rn(v.x); o.y = f2bf_rn(v.y); o.z = f2bf_rn(v.z); o.w = f2bf_rn(v.w);
    ((ushort4*)dst)[off] = o;
    if (i < B_ROWS) amax[i] = 0ull;   // ordered-float 0 == below every real value
    if (i == 0) out[0] = 0.f;
}

// ---------- fused sim GEMM + row argmax ----------
// Single-barrier double-buffered K-loop, unrolled x2 with STATIC LDS buffers:
// the barrier's vmcnt(0) drain waits on loads issued one compute-phase
// earlier instead of just-issued. XCD-swizzled grid keeps each XCD's queue
// slice (~2MB) in its private L2 (R4: FETCH 132->24.6 MB).
#define BM 128
#define BN 128
#define BK 32
#define NCHUNK 8
__global__ __launch_bounds__(256) void sim_argmax_kernel(const unsigned short* __restrict__ A,
                                                         const unsigned short* __restrict__ Bq,
                                                         unsigned long long* __restrict__ amax) {
    __shared__ unsigned short As0[BM * BK], As1[BM * BK];   // 4 x 8 KB, no padding (global_load_lds)
    __shared__ unsigned short Bs0[BN * BK], Bs1[BN * BK];

    const int tid  = threadIdx.x;
    const int wave = tid >> 6;
    const int lane = tid & 63;
    const int l15  = lane & 15;
    const int quad = lane >> 4;

    // XCD-aware swizzle: block i -> XCD i%8 (dispatch heuristic).
    const int bid  = blockIdx.x;
    const int xcd  = bid & 7;
    const int j    = bid >> 3;
    const int blk_m = (j & 31) * BM;
    const int ngrp  = (j >> 5) * 8 + xcd;
    const int nbase = ngrp * (BN * NCHUNK);

    const int wave_m = (wave >> 1) * 64;
    const int wave_n = (wave & 1) * 64;

    // staging: chunk q covers LDS elems [q*512, q*512+512); lane i -> byte q*1024 + i*16
    const int q0 = wave * 2, q1 = wave * 2 + 1;
    const int srow  = lane >> 2;
    const int skoff = (lane & 3) * 8;
    const int row0 = q0 * 16 + srow, row1 = q1 * 16 + srow;

    // per-thread global base pointers (tile t: A + (t&7)*BK, B + (t>>3)*BN*D_K + (t&7)*BK)
    const unsigned short* aP0 = A  + (size_t)(blk_m + row0) * D_K + skoff;
    const unsigned short* aP1 = A  + (size_t)(blk_m + row1) * D_K + skoff;
    const unsigned short* bP0 = Bq + (size_t)(nbase + row0) * D_K + skoff;
    const unsigned short* bP1 = Bq + (size_t)(nbase + row1) * D_K + skoff;

    // fragment LDS element offsets (same for both buffers)
    int aoff[4], boff[4];
#pragma unroll
    for (int mi = 0; mi < 4; mi++) aoff[mi] = (wave_m + mi * 16 + l15) * BK + quad * 8;
#pragma unroll
    for (int ni = 0; ni < 4; ni++) boff[ni] = (wave_n + ni * 16 + l15) * BK + quad * 8;

    float bestv[4][4];
    int   bestc[4][4];
#pragma unroll
    for (int mi = 0; mi < 4; mi++)
#pragma unroll
        for (int reg = 0; reg < 4; reg++) { bestv[mi][reg] = -1e30f; bestc[mi][reg] = 0; }

    f32x4 acc[4][4];
#pragma unroll
    for (int i = 0; i < 4; i++)
#pragma unroll
        for (int jj = 0; jj < 4; jj++) acc[i][jj] = (f32x4){0.f, 0.f, 0.f, 0.f};

#define PREFETCH(T, AS, BS) do {                                                   \
        const int _c  = (T) >> 3;                                                  \
        const int _kb = ((T) & 7) * BK;                                            \
        const size_t _bo = (size_t)_c * (BN * D_K) + _kb;                          \
        __builtin_amdgcn_global_load_lds((gptr1)(aP0 + _kb), (lptr3)&AS[q0 * 512], 16, 0, 0); \
        __builtin_amdgcn_global_load_lds((gptr1)(bP0 + _bo), (lptr3)&BS[q0 * 512], 16, 0, 0); \
        __builtin_amdgcn_global_load_lds((gptr1)(aP1 + _kb), (lptr3)&AS[q1 * 512], 16, 0, 0); \
        __builtin_amdgcn_global_load_lds((gptr1)(bP1 + _bo), (lptr3)&BS[q1 * 512], 16, 0, 0); \
    } while (0)

#define COMPUTE(AS, BS) do {                                                       \
        bf16x8 a_frag[4], b_frag[4];                                               \
        _Pragma("unroll")                                                          \
        for (int mi = 0; mi < 4; mi++) a_frag[mi] = *(const bf16x8*)&AS[aoff[mi]]; \
        _Pragma("unroll")                                                          \
        for (int ni = 0; ni < 4; ni++) b_frag[ni] = *(const bf16x8*)&BS[boff[ni]]; \
        _Pragma("unroll")                                                          \
        for (int mi = 0; mi < 4; mi++)                                             \
            _Pragma("unroll")                                                      \
            for (int ni = 0; ni < 4; ni++)                                         \
                acc[mi][ni] = __builtin_amdgcn_mfma_f32_16x16x32_bf16(a_frag[mi], b_frag[ni], acc[mi][ni], 0, 0, 0); \
    } while (0)

    PREFETCH(0, As0, Bs0);   // prologue: tile 0 -> buf0

#pragma unroll 1
    for (int p = 0; p < 32; ++p) {
        const int t0 = 2 * p;
        __syncthreads();                 // tile t0 (buf0) ready; all waves done reading buf1
        PREFETCH(t0 + 1, As1, Bs1);      // prefetch odd tile -> buf1
        COMPUTE(As0, Bs0);               // compute tile t0
        __syncthreads();                 // tile t0+1 (buf1) ready; all waves done reading buf0
        if (p < 31) PREFETCH(t0 + 2, As0, Bs0);  // prefetch next even tile -> buf0
        COMPUTE(As1, Bs1);               // compute tile t0+1

        if ((p & 3) == 3) {              // chunk c = p>>2 complete: fold, reset acc
            const int col0 = nbase + (p >> 2) * BN + wave_n + l15;
#pragma unroll
            for (int mi = 0; mi < 4; mi++) {
#pragma unroll
                for (int reg = 0; reg < 4; reg++) {
#pragma unroll
                    for (int ni = 0; ni < 4; ni++) {
                        float v = acc[mi][ni][reg];
                        int   c = col0 + ni * 16;
                        if (v > bestv[mi][reg]) { bestv[mi][reg] = v; bestc[mi][reg] = c; }
                    }
                    acc[mi][0][reg] = 0.f; acc[mi][1][reg] = 0.f;
                    acc[mi][2][reg] = 0.f; acc[mi][3][reg] = 0.f;
                }
            }
        }
    }

    // Epilogue (once per block): pack, 16-lane reduce, one atomic per slot
#pragma unroll
    for (int mi = 0; mi < 4; mi++) {
#pragma unroll
        for (int reg = 0; reg < 4; reg++) {
            unsigned long long key =
                ((unsigned long long)f32_ordered(bestv[mi][reg]) << 32) |
                (unsigned long long)(0xFFFFFFFFu - (unsigned)bestc[mi][reg]);   // ~col: ties -> smaller col
#pragma unroll
            for (int m = 1; m < 16; m <<= 1) {
                unsigned long long o = __shfl_xor(key, m, 16);
                if (o > key) key = o;
            }
            if (l15 == mi * 4 + reg) {
                int row = blk_m + wave_m + mi * 16 + quad * 4 + reg;
                atomicMax(&amax[row], key);
            }
        }
    }
}

// ---------- logits + online logsumexp - diag + final reduce (gather inlined) ----------
// one block (8 waves, 512 thr) per 16 rows; waves split the 128 column-tiles
// 16 each, partial (m,l,diag) merged through LDS; block atomicAdds its loss
// contribution into out (zeroed by prep_kernel).
__global__ __launch_bounds__(512) void logits_ce_kernel(const unsigned long long* __restrict__ amax,
                                                        const unsigned short* __restrict__ queue_bf,
                                                        const unsigned short* __restrict__ preds_bf,
                                                        float* __restrict__ out) {
    const int gw   = blockIdx.x;        // 0..255 (16-row group)
    const int tid  = threadIdx.x;
    const int wave = tid >> 6;          // 0..7
    const int lane = tid & 63;
    const int l15  = lane & 15;
    const int quad = lane >> 4;
    const int h    = gw >> 7;           // 0: ab, 1: ba
    const int rowbase = gw * 16;
    const unsigned short* Bbase = preds_bf + (size_t)((1 - h) * HALF) * D_K;

    __shared__ float sm[8][16], sl[8][16], sd[8][16];

    // inline gather: this lane's A-row = queue[argmax(rowbase + l15)]
    unsigned idx = 0xFFFFFFFFu - (unsigned)(amax[rowbase + l15] & 0xFFFFFFFFull);
    const unsigned short* arow = queue_bf + (size_t)idx * D_K;
    bf16x8 a[8];
#pragma unroll
    for (int kc = 0; kc < 8; kc++)
        a[kc] = *(const bf16x8*)&arow[kc * 32 + quad * 8];

    float m_run[4], l_run[4], diag[4];
#pragma unroll
    for (int r = 0; r < 4; r++) { m_run[r] = -1e30f; l_run[r] = 0.f; diag[r] = -1e30f; }

    const int tdiag = gw & 127;
    for (int tt = 0; tt < 16; tt++) {
        const int t = wave * 16 + tt;
        f32x4 acc = (f32x4){0.f, 0.f, 0.f, 0.f};
#pragma unroll
        for (int kc = 0; kc < 8; kc++) {
            bf16x8 b = *(const bf16x8*)&Bbase[(size_t)(t * 16 + l15) * D_K + kc * 32 + quad * 8];
            acc = __builtin_amdgcn_mfma_f32_16x16x32_bf16(a[kc], b, acc, 0, 0, 0);
        }
#pragma unroll
        for (int reg = 0; reg < 4; reg++) {
            float v = acc[reg] * 10.0f;              // 1/TEMPERATURE
            int mrow = quad * 4 + reg;
            if (t == tdiag && l15 == mrow) diag[reg] = v;
            float nm = fmaxf(m_run[reg], v);
            l_run[reg] = l_run[reg] * __expf(m_run[reg] - nm) + __expf(v - nm);
            m_run[reg] = nm;
        }
    }
    // 16-lane merge within the wave
#pragma unroll
    for (int reg = 0; reg < 4; reg++) {
#pragma unroll
        for (int m = 1; m < 16; m <<= 1) {
            float om = __shfl_xor(m_run[reg], m, 16);
            float ol = __shfl_xor(l_run[reg], m, 16);
            float od = __shfl_xor(diag[reg], m, 16);
            float nm = fmaxf(m_run[reg], om);
            l_run[reg] = l_run[reg] * __expf(m_run[reg] - nm) + ol * __expf(om - nm);
            m_run[reg] = nm;
            diag[reg] = fmaxf(diag[reg], od);
        }
        if (l15 == 0) {
            sm[wave][quad * 4 + reg] = m_run[reg];
            sl[wave][quad * 4 + reg] = l_run[reg];
            sd[wave][quad * 4 + reg] = diag[reg];
        }
    }
    __syncthreads();
    // cross-wave merge + block-local reduce + single atomic into out
    if (tid < 16) {
        float M = -1e30f, L = 0.f, Dg = -1e30f;
#pragma unroll
        for (int w = 0; w < 8; w++) {
            float mw = sm[w][tid], lw = sl[w][tid], dw = sd[w][tid];
            float nM = fmaxf(M, mw);
            L = L * __expf(M - nM) + lw * __expf(mw - nM);
            M = nM;
            Dg = fmaxf(Dg, dw);
        }
        float rl = (M + __logf(L)) - Dg;
#pragma unroll
        for (int m = 1; m < 16; m <<= 1) rl += __shfl_xor(rl, m, 16);
        if (tid == 0) atomicAdd(out, rl * (1.0f / (float)B_ROWS));
    }
}

extern "C" void kernel_launch(void* const* d_in, const int* in_sizes, int n_in,
                              void* d_out, int out_size, void* d_ws, size_t ws_size,
                              hipStream_t stream) {
    const float* emb   = (const float*)d_in[0];
    const float* preds = (const float*)d_in[1];
    const float* queue = (const float*)d_in[2];

    char* w = (char*)d_ws;
    unsigned long long* amax   = (unsigned long long*)w;                          // 32 KB
    unsigned short* emb_bf     = (unsigned short*)(w + (64 << 10));               // 2 MB
    unsigned short* preds_bf   = (unsigned short*)(w + (64 << 10) + (2u << 20));  // 2 MB
    unsigned short* queue_bf   = (unsigned short*)(w + (64 << 10) + (4u << 20));  // 32 MB

    prep_kernel<<<dim3((EMB4 + PRED4 + QUE4) / 256), 256, 0, stream>>>(
        emb, preds, queue, emb_bf, preds_bf, queue_bf, amax, (float*)d_out);
    sim_argmax_kernel<<<dim3((B_ROWS / BM) * (Q_ROWS / (BN * NCHUNK))), 256, 0, stream>>>(
        emb_bf, queue_bf, amax);
    logits_ce_kernel<<<dim3(B_ROWS / 16), 512, 0, stream>>>(
        amax, queue_bf, preds_bf, (float*)d_out);
}

// Round 6
// 308.875 us; speedup vs baseline: 1.3382x; 1.0048x over previous
//
#include <hip/hip_runtime.h>
#include <hip/hip_bf16.h>

#define B_ROWS 4096
#define D_K    256
#define Q_ROWS 65536
#define HALF   2048

typedef __bf16 bf16x8 __attribute__((ext_vector_type(8)));
typedef float  f32x4  __attribute__((ext_vector_type(4)));
typedef const __attribute__((address_space(1))) void* gptr1;
typedef __attribute__((address_space(3))) void* lptr3;

__device__ __forceinline__ unsigned int f32_ordered(float f) {
    unsigned int u = __float_as_uint(f);
    return (u & 0x80000000u) ? ~u : (u | 0x80000000u);
}

__device__ __forceinline__ unsigned short f2bf_rn(float f) {
    unsigned int u = __float_as_uint(f);
    u += 0x7FFFu + ((u >> 16) & 1u);
    return (unsigned short)(u >> 16);
}

// ---------- fused prep: f32->bf16 for all 3 inputs + zero amax + zero out ----------
#define EMB4  (B_ROWS * D_K / 4)          // 262144
#define PRED4 (B_ROWS * D_K / 4)          // 262144
#define QUE4  (Q_ROWS * D_K / 4)          // 4194304
__global__ __launch_bounds__(256) void prep_kernel(const float* __restrict__ emb,
                                                   const float* __restrict__ preds,
                                                   const float* __restrict__ queue,
                                                   unsigned short* __restrict__ emb_bf,
                                                   unsigned short* __restrict__ preds_bf,
                                                   unsigned short* __restrict__ queue_bf,
                                                   unsigned long long* __restrict__ amax,
                                                   float* __restrict__ out) {
    int i = blockIdx.x * 256 + threadIdx.x;
    const float* src;
    unsigned short* dst;
    int off;
    if (i < EMB4)              { src = emb;   dst = emb_bf;   off = i; }
    else if (i < EMB4 + PRED4) { src = preds; dst = preds_bf; off = i - EMB4; }
    else                       { src = queue; dst = queue_bf; off = i - EMB4 - PRED4; }
    float4 v = ((const float4*)src)[off];
    ushort4 o;
    o.x = f2bf_rn(v.x); o.y = f2bf_rn(v.y); o.z = f2bf_rn(v.z); o.w = f2bf_rn(v.w);
    ((ushort4*)dst)[off] = o;
    if (i < B_ROWS) amax[i] = 0ull;   // ordered-float 0 == below every real value
    if (i == 0) out[0] = 0.f;
}

// ---------- fused sim GEMM + row argmax ----------
// BM=256 x BN=128 tile, 8 waves (4x2 grid of 64x64 wave-tiles). Single-barrier
// double-buffered K-loop with STATIC LDS buffers; 3 global_load_lds per thread
// per tile (A:2, B:1). XCD-swizzled grid keeps each XCD's queue slice in its
// private L2 (R4: FETCH 132->24.6 MB). 2x FLOP per barrier + ~16 waves/CU vs
// R5's 7 attacks the exposed staging latency.
#define BM 256
#define BN 128
#define BK 32
#define NCHUNK 8
__global__ __launch_bounds__(512) void sim_argmax_kernel(const unsigned short* __restrict__ A,
                                                         const unsigned short* __restrict__ Bq,
                                                         unsigned long long* __restrict__ amax) {
    __shared__ unsigned short As0[BM * BK], As1[BM * BK];   // 2 x 16 KB (no padding: global_load_lds)
    __shared__ unsigned short Bs0[BN * BK], Bs1[BN * BK];   // 2 x 8 KB

    const int tid  = threadIdx.x;
    const int wave = tid >> 6;          // 0..7
    const int lane = tid & 63;
    const int l15  = lane & 15;
    const int quad = lane >> 4;

    // XCD-aware swizzle: block i -> XCD i%8 (dispatch heuristic).
    const int bid  = blockIdx.x;
    const int xcd  = bid & 7;
    const int j    = bid >> 3;          // 0..127
    const int blk_m = (j & 15) * BM;    // 16 m-blocks
    const int ngrp  = (j >> 4) * 8 + xcd;   // 64 n-groups
    const int nbase = ngrp * (BN * NCHUNK);

    const int wave_m = (wave >> 1) * 64;    // 0,64,128,192
    const int wave_n = (wave & 1) * 64;     // 0,64

    // staging: chunk q covers LDS elems [q*512, q*512+512) (16 rows x 32 elems);
    // lane i -> byte q*1024 + i*16. A: 16 chunks (2/wave), B: 8 chunks (1/wave).
    const int srow  = lane >> 2;
    const int skoff = (lane & 3) * 8;
    const int qa0 = wave * 2, qa1 = wave * 2 + 1;

    const unsigned short* aP0 = A  + (size_t)(blk_m + qa0 * 16 + srow) * D_K + skoff;
    const unsigned short* aP1 = A  + (size_t)(blk_m + qa1 * 16 + srow) * D_K + skoff;
    const unsigned short* bP  = Bq + (size_t)(nbase + wave * 16 + srow) * D_K + skoff;

    // fragment LDS element offsets (same for both buffers)
    int aoff[4], boff[4];
#pragma unroll
    for (int mi = 0; mi < 4; mi++) aoff[mi] = (wave_m + mi * 16 + l15) * BK + quad * 8;
#pragma unroll
    for (int ni = 0; ni < 4; ni++) boff[ni] = (wave_n + ni * 16 + l15) * BK + quad * 8;

    float bestv[4][4];
    int   bestc[4][4];
#pragma unroll
    for (int mi = 0; mi < 4; mi++)
#pragma unroll
        for (int reg = 0; reg < 4; reg++) { bestv[mi][reg] = -1e30f; bestc[mi][reg] = 0; }

    f32x4 acc[4][4];
#pragma unroll
    for (int i = 0; i < 4; i++)
#pragma unroll
        for (int jj = 0; jj < 4; jj++) acc[i][jj] = (f32x4){0.f, 0.f, 0.f, 0.f};

#define PREFETCH(T, AS, BS) do {                                                   \
        const int _kb = ((T) & 7) * BK;                                            \
        const size_t _bo = (size_t)((T) >> 3) * (BN * D_K) + _kb;                  \
        __builtin_amdgcn_global_load_lds((gptr1)(aP0 + _kb), (lptr3)&AS[qa0 * 512], 16, 0, 0); \
        __builtin_amdgcn_global_load_lds((gptr1)(aP1 + _kb), (lptr3)&AS[qa1 * 512], 16, 0, 0); \
        __builtin_amdgcn_global_load_lds((gptr1)(bP + _bo),  (lptr3)&BS[wave * 512], 16, 0, 0); \
    } while (0)

#define COMPUTE(AS, BS) do {                                                       \
        bf16x8 a_frag[4], b_frag[4];                                               \
        _Pragma("unroll")                                                          \
        for (int mi = 0; mi < 4; mi++) a_frag[mi] = *(const bf16x8*)&AS[aoff[mi]]; \
        _Pragma("unroll")                                                          \
        for (int ni = 0; ni < 4; ni++) b_frag[ni] = *(const bf16x8*)&BS[boff[ni]]; \
        _Pragma("unroll")                                                          \
        for (int mi = 0; mi < 4; mi++)                                             \
            _Pragma("unroll")                                                      \
            for (int ni = 0; ni < 4; ni++)                                         \
                acc[mi][ni] = __builtin_amdgcn_mfma_f32_16x16x32_bf16(a_frag[mi], b_frag[ni], acc[mi][ni], 0, 0, 0); \
    } while (0)

    PREFETCH(0, As0, Bs0);   // prologue: tile 0 -> buf0

#pragma unroll 1
    for (int p = 0; p < 32; ++p) {
        const int t0 = 2 * p;
        __syncthreads();                 // tile t0 (buf0) ready; all waves done reading buf1
        PREFETCH(t0 + 1, As1, Bs1);      // prefetch odd tile -> buf1
        COMPUTE(As0, Bs0);               // compute tile t0
        __syncthreads();                 // tile t0+1 (buf1) ready; all waves done reading buf0
        if (p < 31) PREFETCH(t0 + 2, As0, Bs0);  // prefetch next even tile -> buf0
        COMPUTE(As1, Bs1);               // compute tile t0+1

        if ((p & 3) == 3) {              // chunk c = p>>2 complete: fold, reset acc
            const int col0 = nbase + (p >> 2) * BN + wave_n + l15;
#pragma unroll
            for (int mi = 0; mi < 4; mi++) {
#pragma unroll
                for (int reg = 0; reg < 4; reg++) {
#pragma unroll
                    for (int ni = 0; ni < 4; ni++) {
                        float v = acc[mi][ni][reg];
                        int   c = col0 + ni * 16;
                        if (v > bestv[mi][reg]) { bestv[mi][reg] = v; bestc[mi][reg] = c; }
                    }
                    acc[mi][0][reg] = 0.f; acc[mi][1][reg] = 0.f;
                    acc[mi][2][reg] = 0.f; acc[mi][3][reg] = 0.f;
                }
            }
        }
    }

    // Epilogue (once per block): pack, 16-lane reduce, one atomic per slot
#pragma unroll
    for (int mi = 0; mi < 4; mi++) {
#pragma unroll
        for (int reg = 0; reg < 4; reg++) {
            unsigned long long key =
                ((unsigned long long)f32_ordered(bestv[mi][reg]) << 32) |
                (unsigned long long)(0xFFFFFFFFu - (unsigned)bestc[mi][reg]);   // ~col: ties -> smaller col
#pragma unroll
            for (int m = 1; m < 16; m <<= 1) {
                unsigned long long o = __shfl_xor(key, m, 16);
                if (o > key) key = o;
            }
            if (l15 == mi * 4 + reg) {
                int row = blk_m + wave_m + mi * 16 + quad * 4 + reg;
                atomicMax(&amax[row], key);
            }
        }
    }
}

// ---------- logits + online logsumexp - diag + final reduce (gather inlined) ----------
// one block (8 waves, 512 thr) per 16 rows; waves split the 128 column-tiles
// 16 each, partial (m,l,diag) merged through LDS; block atomicAdds its loss
// contribution into out (zeroed by prep_kernel).
__global__ __launch_bounds__(512) void logits_ce_kernel(const unsigned long long* __restrict__ amax,
                                                        const unsigned short* __restrict__ queue_bf,
                                                        const unsigned short* __restrict__ preds_bf,
                                                        float* __restrict__ out) {
    const int gw   = blockIdx.x;        // 0..255 (16-row group)
    const int tid  = threadIdx.x;
    const int wave = tid >> 6;          // 0..7
    const int lane = tid & 63;
    const int l15  = lane & 15;
    const int quad = lane >> 4;
    const int h    = gw >> 7;           // 0: ab, 1: ba
    const int rowbase = gw * 16;
    const unsigned short* Bbase = preds_bf + (size_t)((1 - h) * HALF) * D_K;

    __shared__ float sm[8][16], sl[8][16], sd[8][16];

    // inline gather: this lane's A-row = queue[argmax(rowbase + l15)]
    unsigned idx = 0xFFFFFFFFu - (unsigned)(amax[rowbase + l15] & 0xFFFFFFFFull);
    const unsigned short* arow = queue_bf + (size_t)idx * D_K;
    bf16x8 a[8];
#pragma unroll
    for (int kc = 0; kc < 8; kc++)
        a[kc] = *(const bf16x8*)&arow[kc * 32 + quad * 8];

    float m_run[4], l_run[4], diag[4];
#pragma unroll
    for (int r = 0; r < 4; r++) { m_run[r] = -1e30f; l_run[r] = 0.f; diag[r] = -1e30f; }

    const int tdiag = gw & 127;
    for (int tt = 0; tt < 16; tt++) {
        const int t = wave * 16 + tt;
        f32x4 acc = (f32x4){0.f, 0.f, 0.f, 0.f};
#pragma unroll
        for (int kc = 0; kc < 8; kc++) {
            bf16x8 b = *(const bf16x8*)&Bbase[(size_t)(t * 16 + l15) * D_K + kc * 32 + quad * 8];
            acc = __builtin_amdgcn_mfma_f32_16x16x32_bf16(a[kc], b, acc, 0, 0, 0);
        }
#pragma unroll
        for (int reg = 0; reg < 4; reg++) {
            float v = acc[reg] * 10.0f;              // 1/TEMPERATURE
            int mrow = quad * 4 + reg;
            if (t == tdiag && l15 == mrow) diag[reg] = v;
            float nm = fmaxf(m_run[reg], v);
            l_run[reg] = l_run[reg] * __expf(m_run[reg] - nm) + __expf(v - nm);
            m_run[reg] = nm;
        }
    }
    // 16-lane merge within the wave
#pragma unroll
    for (int reg = 0; reg < 4; reg++) {
#pragma unroll
        for (int m = 1; m < 16; m <<= 1) {
            float om = __shfl_xor(m_run[reg], m, 16);
            float ol = __shfl_xor(l_run[reg], m, 16);
            float od = __shfl_xor(diag[reg], m, 16);
            float nm = fmaxf(m_run[reg], om);
            l_run[reg] = l_run[reg] * __expf(m_run[reg] - nm) + ol * __expf(om - nm);
            m_run[reg] = nm;
            diag[reg] = fmaxf(diag[reg], od);
        }
        if (l15 == 0) {
            sm[wave][quad * 4 + reg] = m_run[reg];
            sl[wave][quad * 4 + reg] = l_run[reg];
            sd[wave][quad * 4 + reg] = diag[reg];
        }
    }
    __syncthreads();
    // cross-wave merge + block-local reduce + single atomic into out
    if (tid < 16) {
        float M = -1e30f, L = 0.f, Dg = -1e30f;
#pragma unroll
        for (int w = 0; w < 8; w++) {
            float mw = sm[w][tid], lw = sl[w][tid], dw = sd[w][tid];
            float nM = fmaxf(M, mw);
            L = L * __expf(M - nM) + lw * __expf(mw - nM);
            M = nM;
            Dg = fmaxf(Dg, dw);
        }
        float rl = (M + __logf(L)) - Dg;
#pragma unroll
        for (int m = 1; m < 16; m <<= 1) rl += __shfl_xor(rl, m, 16);
        if (tid == 0) atomicAdd(out, rl * (1.0f / (float)B_ROWS));
    }
}

extern "C" void kernel_launch(void* const* d_in, const int* in_sizes, int n_in,
                              void* d_out, int out_size, void* d_ws, size_t ws_size,
                              hipStream_t stream) {
    const float* emb   = (const float*)d_in[0];
    const float* preds = (const float*)d_in[1];
    const float* queue = (const float*)d_in[2];

    char* w = (char*)d_ws;
    unsigned long long* amax   = (unsigned long long*)w;                          // 32 KB
    unsigned short* emb_bf     = (unsigned short*)(w + (64 << 10));               // 2 MB
    unsigned short* preds_bf   = (unsigned short*)(w + (64 << 10) + (2u << 20));  // 2 MB
    unsigned short* queue_bf   = (unsigned short*)(w + (64 << 10) + (4u << 20));  // 32 MB

    prep_kernel<<<dim3((EMB4 + PRED4 + QUE4) / 256), 256, 0, stream>>>(
        emb, preds, queue, emb_bf, preds_bf, queue_bf, amax, (float*)d_out);
    sim_argmax_kernel<<<dim3((B_ROWS / BM) * (Q_ROWS / (BN * NCHUNK))), 512, 0, stream>>>(
        emb_bf, queue_bf, amax);
    logits_ce_kernel<<<dim3(B_ROWS / 16), 512, 0, stream>>>(
        amax, queue_bf, preds_bf, (float*)d_out);
}

// Round 7
// 299.414 us; speedup vs baseline: 1.3805x; 1.0316x over previous
//
#include <hip/hip_runtime.h>
#include <hip/hip_bf16.h>

#define B_ROWS 4096
#define D_K    256
#define Q_ROWS 65536
#define HALF   2048

typedef __bf16 bf16x8 __attribute__((ext_vector_type(8)));
typedef float  f32x4  __attribute__((ext_vector_type(4)));
typedef const __attribute__((address_space(1))) void* gptr1;
typedef __attribute__((address_space(3))) void* lptr3;

__device__ __forceinline__ unsigned int f32_ordered(float f) {
    unsigned int u = __float_as_uint(f);
    return (u & 0x80000000u) ? ~u : (u | 0x80000000u);
}

__device__ __forceinline__ unsigned short f2bf_rn(float f) {
    unsigned int u = __float_as_uint(f);
    u += 0x7FFFu + ((u >> 16) & 1u);
    return (unsigned short)(u >> 16);
}

// ---------- fused prep: f32->bf16 for all 3 inputs + zero amax + zero out ----------
#define EMB4  (B_ROWS * D_K / 4)          // 262144
#define PRED4 (B_ROWS * D_K / 4)          // 262144
#define QUE4  (Q_ROWS * D_K / 4)          // 4194304
__global__ __launch_bounds__(256) void prep_kernel(const float* __restrict__ emb,
                                                   const float* __restrict__ preds,
                                                   const float* __restrict__ queue,
                                                   unsigned short* __restrict__ emb_bf,
                                                   unsigned short* __restrict__ preds_bf,
                                                   unsigned short* __restrict__ queue_bf,
                                                   unsigned long long* __restrict__ amax,
                                                   float* __restrict__ out) {
    int i = blockIdx.x * 256 + threadIdx.x;
    const float* src;
    unsigned short* dst;
    int off;
    if (i < EMB4)              { src = emb;   dst = emb_bf;   off = i; }
    else if (i < EMB4 + PRED4) { src = preds; dst = preds_bf; off = i - EMB4; }
    else                       { src = queue; dst = queue_bf; off = i - EMB4 - PRED4; }
    float4 v = ((const float4*)src)[off];
    ushort4 o;
    o.x = f2bf_rn(v.x); o.y = f2bf_rn(v.y); o.z = f2bf_rn(v.z); o.w = f2bf_rn(v.w);
    ((ushort4*)dst)[off] = o;
    if (i < B_ROWS) amax[i] = 0ull;   // ordered-float 0 == below every real value
    if (i == 0) out[0] = 0.f;
}

// ---------- fused sim GEMM + row argmax ----------
// BM=128, 4 waves. A (emb tile) staged ONCE per block into 64KB LDS; per-tile
// staging is B only (double-buffered 2x8KB, single-barrier pipeline). All LDS
// rows are kgroup-XOR-swizzled (A: kg^=row&7, B: kg^=row&3) so the 16-lane
// ds_read_b128 fragment reads spread over 8 bank-groups -> 2-way (free)
// instead of 8-way conflict. LDS 80KB -> 2 blocks/CU, stalls interleave.
#define BM 128
#define BN 128
#define BK 32
#define NCHUNK 8
__global__ __launch_bounds__(256) void sim_argmax_kernel(const unsigned short* __restrict__ A,
                                                         const unsigned short* __restrict__ Bq,
                                                         unsigned long long* __restrict__ amax) {
    __shared__ unsigned short Asw[BM * D_K];            // 64 KB, staged once, swizzled
    __shared__ unsigned short Bs0[BN * BK], Bs1[BN * BK];  // 2 x 8 KB dbuf, swizzled

    const int tid  = threadIdx.x;
    const int wave = tid >> 6;          // 0..3
    const int lane = tid & 63;
    const int l15  = lane & 15;
    const int quad = lane >> 4;

    // XCD-aware swizzle: block i -> XCD i%8 (dispatch heuristic).
    const int bid  = blockIdx.x;
    const int xcd  = bid & 7;
    const int j    = bid >> 3;
    const int blk_m = (j & 31) * BM;
    const int ngrp  = (j >> 5) * 8 + xcd;
    const int nbase = ngrp * (BN * NCHUNK);

    const int wave_m = (wave >> 1) * 64;
    const int wave_n = (wave & 1) * 64;

    // ---- stage A once: 16 issues; lane l of wave w, issue j covers LDS bytes
    // j*4096 + w*1024 + l*16 -> row = j*8 + w*2 + (l>>5), kg_stored = l&31.
    // Swizzle: fetch global kg = kg_stored ^ (row&7).
    {
        const int rsub = wave * 2 + (lane >> 5);      // row & 7 (j*8 contributes 0)
        const int kgg  = (lane & 31) ^ rsub;
#pragma unroll
        for (int jj = 0; jj < 16; jj++) {
            const int row = jj * 8 + rsub;
            const unsigned short* ga = A + (size_t)(blk_m + row) * D_K + kgg * 8;
            __builtin_amdgcn_global_load_lds((gptr1)ga, (lptr3)&Asw[jj * 2048 + wave * 512], 16, 0, 0);
        }
    }

    // ---- B staging bases: wave stages chunks q0=2w, q1=2w+1 (16 rows each).
    // lane l: row_in_chunk = l>>2, kg_stored = l&3, global kg = (l&3)^((l>>2)&3).
    const int q0 = wave * 2, q1 = wave * 2 + 1;
    const int brow = lane >> 2;
    const int bkg  = ((lane & 3) ^ (brow & 3)) * 8;
    const unsigned short* bPa = Bq + (size_t)(nbase + q0 * 16 + brow) * D_K + bkg;
    const unsigned short* bPb = Bq + (size_t)(nbase + q1 * 16 + brow) * D_K + bkg;

    // ---- fragment read offsets
    const int axor = l15 & 7;           // (R&7) for A rows
    const int bxor = l15 & 3;           // (R&3) for B rows
    int aoffb[4], boff[4];
#pragma unroll
    for (int mi = 0; mi < 4; mi++) aoffb[mi] = (wave_m + mi * 16 + l15) * D_K;
#pragma unroll
    for (int ni = 0; ni < 4; ni++) boff[ni] = (wave_n + ni * 16 + l15) * BK + (quad ^ bxor) * 8;

    float bestv[4][4];
    int   bestc[4][4];
#pragma unroll
    for (int mi = 0; mi < 4; mi++)
#pragma unroll
        for (int reg = 0; reg < 4; reg++) { bestv[mi][reg] = -1e30f; bestc[mi][reg] = 0; }

    f32x4 acc[4][4];
#pragma unroll
    for (int i = 0; i < 4; i++)
#pragma unroll
        for (int jj = 0; jj < 4; jj++) acc[i][jj] = (f32x4){0.f, 0.f, 0.f, 0.f};

#define PREFB(T, BS) do {                                                          \
        const size_t _bo = (size_t)((T) >> 3) * (BN * D_K) + ((T) & 7) * BK;       \
        __builtin_amdgcn_global_load_lds((gptr1)(bPa + _bo), (lptr3)&BS[q0 * 512], 16, 0, 0); \
        __builtin_amdgcn_global_load_lds((gptr1)(bPb + _bo), (lptr3)&BS[q1 * 512], 16, 0, 0); \
    } while (0)

#define COMPUTE(BS, KT) do {                                                       \
        const int _ksw = (((KT) << 2) | quad) ^ axor;                              \
        bf16x8 af[4], bf[4];                                                       \
        _Pragma("unroll")                                                          \
        for (int mi = 0; mi < 4; mi++) af[mi] = *(const bf16x8*)&Asw[aoffb[mi] + _ksw * 8]; \
        _Pragma("unroll")                                                          \
        for (int ni = 0; ni < 4; ni++) bf[ni] = *(const bf16x8*)&BS[boff[ni]];     \
        _Pragma("unroll")                                                          \
        for (int mi = 0; mi < 4; mi++)                                             \
            _Pragma("unroll")                                                      \
            for (int ni = 0; ni < 4; ni++)                                         \
                acc[mi][ni] = __builtin_amdgcn_mfma_f32_16x16x32_bf16(af[mi], bf[ni], acc[mi][ni], 0, 0, 0); \
    } while (0)

    PREFB(0, Bs0);   // prologue: B tile 0 -> buf0 (A issues already in flight)

#pragma unroll 1
    for (int p = 0; p < 32; ++p) {
        const int t0 = 2 * p;
        __syncthreads();                 // vmcnt(0): A (1st iter) + B tile t0 ready
        PREFB(t0 + 1, Bs1);
        COMPUTE(Bs0, t0 & 7);
        __syncthreads();                 // B tile t0+1 ready; all waves done with Bs0
        if (p < 31) PREFB(t0 + 2, Bs0);
        COMPUTE(Bs1, (t0 + 1) & 7);

        if ((p & 3) == 3) {              // n-chunk p>>2 complete: fold, reset acc
            const int col0 = nbase + (p >> 2) * BN + wave_n + l15;
#pragma unroll
            for (int mi = 0; mi < 4; mi++) {
#pragma unroll
                for (int reg = 0; reg < 4; reg++) {
#pragma unroll
                    for (int ni = 0; ni < 4; ni++) {
                        float v = acc[mi][ni][reg];
                        int   c = col0 + ni * 16;
                        if (v > bestv[mi][reg]) { bestv[mi][reg] = v; bestc[mi][reg] = c; }
                    }
                    acc[mi][0][reg] = 0.f; acc[mi][1][reg] = 0.f;
                    acc[mi][2][reg] = 0.f; acc[mi][3][reg] = 0.f;
                }
            }
        }
    }

    // Epilogue (once per block): pack, 16-lane reduce, one atomic per slot
#pragma unroll
    for (int mi = 0; mi < 4; mi++) {
#pragma unroll
        for (int reg = 0; reg < 4; reg++) {
            unsigned long long key =
                ((unsigned long long)f32_ordered(bestv[mi][reg]) << 32) |
                (unsigned long long)(0xFFFFFFFFu - (unsigned)bestc[mi][reg]);   // ~col: ties -> smaller col
#pragma unroll
            for (int m = 1; m < 16; m <<= 1) {
                unsigned long long o = __shfl_xor(key, m, 16);
                if (o > key) key = o;
            }
            if (l15 == mi * 4 + reg) {
                int row = blk_m + wave_m + mi * 16 + quad * 4 + reg;
                atomicMax(&amax[row], key);
            }
        }
    }
}

// ---------- logits + two-pass logsumexp - diag + final reduce (gather inlined) ----------
// one block (8 waves, 512 thr) per 16 rows; waves split the 128 column-tiles
// 16 each. Pass 1: MFMA all tiles, stash 64 vals/lane in regs, online max only.
// Pass 2: single exp sweep. Merged across lanes/waves through LDS.
__global__ __launch_bounds__(512) void logits_ce_kernel(const unsigned long long* __restrict__ amax,
                                                        const unsigned short* __restrict__ queue_bf,
                                                        const unsigned short* __restrict__ preds_bf,
                                                        float* __restrict__ out) {
    const int gw   = blockIdx.x;        // 0..255 (16-row group)
    const int tid  = threadIdx.x;
    const int wave = tid >> 6;          // 0..7
    const int lane = tid & 63;
    const int l15  = lane & 15;
    const int quad = lane >> 4;
    const int h    = gw >> 7;           // 0: ab, 1: ba
    const int rowbase = gw * 16;
    const unsigned short* Bbase = preds_bf + (size_t)((1 - h) * HALF) * D_K;

    __shared__ float sm[8][16], sl[8][16], sd[8][16];

    // inline gather: this lane's A-row = queue[argmax(rowbase + l15)]
    unsigned idx = 0xFFFFFFFFu - (unsigned)(amax[rowbase + l15] & 0xFFFFFFFFull);
    const unsigned short* arow = queue_bf + (size_t)idx * D_K;
    bf16x8 a[8];
#pragma unroll
    for (int kc = 0; kc < 8; kc++)
        a[kc] = *(const bf16x8*)&arow[kc * 32 + quad * 8];

    float vals[16][4];
    float m_run[4], diag[4];
#pragma unroll
    for (int r = 0; r < 4; r++) { m_run[r] = -1e30f; diag[r] = -1e30f; }

    const int tdiag = gw & 127;
#pragma unroll 2
    for (int tt = 0; tt < 16; tt++) {
        const int t = wave * 16 + tt;
        f32x4 acc = (f32x4){0.f, 0.f, 0.f, 0.f};
#pragma unroll
        for (int kc = 0; kc < 8; kc++) {
            bf16x8 b = *(const bf16x8*)&Bbase[(size_t)(t * 16 + l15) * D_K + kc * 32 + quad * 8];
            acc = __builtin_amdgcn_mfma_f32_16x16x32_bf16(a[kc], b, acc, 0, 0, 0);
        }
#pragma unroll
        for (int reg = 0; reg < 4; reg++) {
            float v = acc[reg] * 10.0f;              // 1/TEMPERATURE
            vals[tt][reg] = v;
            if (t == tdiag && l15 == quad * 4 + reg) diag[reg] = v;
            m_run[reg] = fmaxf(m_run[reg], v);
        }
    }
    float l_run[4];
#pragma unroll
    for (int reg = 0; reg < 4; reg++) {
        float s = 0.f;
#pragma unroll
        for (int tt = 0; tt < 16; tt++)
            s += __expf(vals[tt][reg] - m_run[reg]);
        l_run[reg] = s;
    }
    // 16-lane merge within the wave
#pragma unroll
    for (int reg = 0; reg < 4; reg++) {
#pragma unroll
        for (int m = 1; m < 16; m <<= 1) {
            float om = __shfl_xor(m_run[reg], m, 16);
            float ol = __shfl_xor(l_run[reg], m, 16);
            float od = __shfl_xor(diag[reg], m, 16);
            float nm = fmaxf(m_run[reg], om);
            l_run[reg] = l_run[reg] * __expf(m_run[reg] - nm) + ol * __expf(om - nm);
            m_run[reg] = nm;
            diag[reg] = fmaxf(diag[reg], od);
        }
        if (l15 == 0) {
            sm[wave][quad * 4 + reg] = m_run[reg];
            sl[wave][quad * 4 + reg] = l_run[reg];
            sd[wave][quad * 4 + reg] = diag[reg];
        }
    }
    __syncthreads();
    // cross-wave merge + block-local reduce + single atomic into out
    if (tid < 16) {
        float M = -1e30f, L = 0.f, Dg = -1e30f;
#pragma unroll
        for (int w = 0; w < 8; w++) {
            float mw = sm[w][tid], lw = sl[w][tid], dw = sd[w][tid];
            float nM = fmaxf(M, mw);
            L = L * __expf(M - nM) + lw * __expf(mw - nM);
            M = nM;
            Dg = fmaxf(Dg, dw);
        }
        float rl = (M + __logf(L)) - Dg;
#pragma unroll
        for (int m = 1; m < 16; m <<= 1) rl += __shfl_xor(rl, m, 16);
        if (tid == 0) atomicAdd(out, rl * (1.0f / (float)B_ROWS));
    }
}

extern "C" void kernel_launch(void* const* d_in, const int* in_sizes, int n_in,
                              void* d_out, int out_size, void* d_ws, size_t ws_size,
                              hipStream_t stream) {
    const float* emb   = (const float*)d_in[0];
    const float* preds = (const float*)d_in[1];
    const float* queue = (const float*)d_in[2];

    char* w = (char*)d_ws;
    unsigned long long* amax   = (unsigned long long*)w;                          // 32 KB
    unsigned short* emb_bf     = (unsigned short*)(w + (64 << 10));               // 2 MB
    unsigned short* preds_bf   = (unsigned short*)(w + (64 << 10) + (2u << 20));  // 2 MB
    unsigned short* queue_bf   = (unsigned short*)(w + (64 << 10) + (4u << 20));  // 32 MB

    prep_kernel<<<dim3((EMB4 + PRED4 + QUE4) / 256), 256, 0, stream>>>(
        emb, preds, queue, emb_bf, preds_bf, queue_bf, amax, (float*)d_out);
    sim_argmax_kernel<<<dim3((B_ROWS / BM) * (Q_ROWS / (BN * NCHUNK))), 256, 0, stream>>>(
        emb_bf, queue_bf, amax);
    logits_ce_kernel<<<dim3(B_ROWS / 16), 512, 0, stream>>>(
        amax, queue_bf, preds_bf, (float*)d_out);
}

// Round 8
// 213.836 us; speedup vs baseline: 1.9330x; 1.4002x over previous
//
#include <hip/hip_runtime.h>
#include <hip/hip_bf16.h>
#include <stdint.h>

#define B_ROWS 4096
#define D_K    256
#define Q_ROWS 65536
#define HALF   2048

typedef __bf16 bf16x8 __attribute__((ext_vector_type(8)));
typedef float  f32x4  __attribute__((ext_vector_type(4)));
typedef int    v8i    __attribute__((ext_vector_type(8)));
typedef int    v4i    __attribute__((ext_vector_type(4)));
typedef unsigned short u16x8 __attribute__((ext_vector_type(8)));
typedef const __attribute__((address_space(1))) void* gptr1;
typedef __attribute__((address_space(3))) void* lptr3;

__device__ __forceinline__ unsigned int f32_ordered(float f) {
    unsigned int u = __float_as_uint(f);
    return (u & 0x80000000u) ? ~u : (u | 0x80000000u);
}

__device__ __forceinline__ unsigned short f2bf_rn(float f) {
    unsigned int u = __float_as_uint(f);
    u += 0x7FFFu + ((u >> 16) & 1u);
    return (unsigned short)(u >> 16);
}

// ---------- fused prep: emb/queue -> fp8 e4m3, preds -> bf16, zero amax/out ----------
#define EMB4  (B_ROWS * D_K / 4)          // 262144
#define PRED4 (B_ROWS * D_K / 4)          // 262144
#define QUE4  (Q_ROWS * D_K / 4)          // 4194304
__global__ __launch_bounds__(256) void prep_kernel(const float* __restrict__ emb,
                                                   const float* __restrict__ preds,
                                                   const float* __restrict__ queue,
                                                   unsigned char* __restrict__ emb8,
                                                   unsigned short* __restrict__ preds_bf,
                                                   unsigned char* __restrict__ queue8,
                                                   unsigned long long* __restrict__ amax,
                                                   float* __restrict__ out) {
    int i = blockIdx.x * 256 + threadIdx.x;
    if (i < EMB4) {
        float4 v = ((const float4*)emb)[i];
        int u = __builtin_amdgcn_cvt_pk_fp8_f32(v.x, v.y, 0, false);
        u     = __builtin_amdgcn_cvt_pk_fp8_f32(v.z, v.w, u, true);
        ((int*)emb8)[i] = u;
    } else if (i < EMB4 + PRED4) {
        int off = i - EMB4;
        float4 v = ((const float4*)preds)[off];
        ushort4 o;
        o.x = f2bf_rn(v.x); o.y = f2bf_rn(v.y); o.z = f2bf_rn(v.z); o.w = f2bf_rn(v.w);
        ((ushort4*)preds_bf)[off] = o;
    } else {
        int off = i - EMB4 - PRED4;
        float4 v = ((const float4*)queue)[off];
        int u = __builtin_amdgcn_cvt_pk_fp8_f32(v.x, v.y, 0, false);
        u     = __builtin_amdgcn_cvt_pk_fp8_f32(v.z, v.w, u, true);
        ((int*)queue8)[off] = u;
    }
    if (i < B_ROWS) amax[i] = 0ull;   // ordered-float 0 == below every real value
    if (i == 0) out[0] = 0.f;
}

// ---------- fused sim GEMM + row argmax, MX-fp8 (scale=1.0) ----------
// mfma_scale_f32_16x16x128_f8f6f4: 2x bf16 MFMA rate, half staging bytes,
// BK=128 -> 16 barriers/block (vs 64). A (128x256 fp8 = 32 KB) staged once,
// B dbuf 2x16 KB, single-barrier pipeline. 16-B granules XOR-swizzled by row
// so fragment ds-reads spread uniformly over banks. XCD-swizzled grid keeps
// each XCD's queue slice in its private L2 (R4: FETCH 132->24.6 MB).
#define BM 128
#define BN 128
#define NCHUNK 8
#define MFMA_FP8(av, bv, c) \
    __builtin_amdgcn_mfma_scale_f32_16x16x128_f8f6f4((av), (bv), (c), 0, 0, 0, 0x7F7F7F7F, 0, 0x7F7F7F7F)

__global__ __launch_bounds__(256, 2) void sim_argmax_kernel(const unsigned char* __restrict__ A8,
                                                            const unsigned char* __restrict__ B8,
                                                            unsigned long long* __restrict__ amax) {
    __shared__ unsigned char Asw[BM * D_K];          // 32 KB, staged once, swizzled
    __shared__ unsigned char Bs0[BN * 128];          // 16 KB dbuf, swizzled
    __shared__ unsigned char Bs1[BN * 128];

    const int tid  = threadIdx.x;
    const int wave = tid >> 6;          // 0..3
    const int lane = tid & 63;
    const int l15  = lane & 15;
    const int quad = lane >> 4;

    // XCD-aware swizzle: block i -> XCD i%8 (dispatch heuristic).
    const int bid  = blockIdx.x;
    const int xcd  = bid & 7;
    const int j    = bid >> 3;
    const int blk_m = (j & 31) * BM;
    const int ngrp  = (j >> 5) * 8 + xcd;
    const int nbase = ngrp * (BN * NCHUNK);

    const int wave_m = (wave >> 1) * 64;
    const int wave_n = (wave & 1) * 64;

    // ---- stage A once (8 issues): LDS byte j*4096 + tid*16 holds row
    // r = j*16 + (tid>>4), slot tid&15; global granule g = slot ^ (r&15).
    {
        const unsigned char* gA = A8 + (size_t)(blk_m + (tid >> 4)) * D_K
                                     + (((tid & 15) ^ ((tid >> 4) & 15)) << 4);
#pragma unroll
        for (int jj = 0; jj < 8; jj++)
            __builtin_amdgcn_global_load_lds((gptr1)(gA + jj * 4096),
                                             (lptr3)&Asw[jj * 4096 + wave * 1024], 16, 0, 0);
    }

    // ---- B staging base: issue j covers rows j*32 + (tid>>3), slot tid&7,
    // global granule g = slot ^ (r&7). Tile T: +(T>>1)*32768 + (T&1)*128 bytes.
    const unsigned char* gB = B8 + (size_t)(nbase + (tid >> 3)) * D_K
                                 + (((tid & 7) ^ ((tid >> 3) & 7)) << 4);

#define PREFB(T, BS) do {                                                              \
        const int _off = ((T) >> 1) * (32 * D_K * 4) + ((T) & 1) * 128;                \
        _Pragma("unroll")                                                              \
        for (int _j = 0; _j < 4; _j++)                                                 \
            __builtin_amdgcn_global_load_lds((gptr1)(gB + _j * 8192 + _off),           \
                                             (lptr3)&BS[_j * 4096 + wave * 1024], 16, 0, 0); \
    } while (0)

    // ---- fragment read bases (byte offsets) and swizzle keys
    int Abase[4], Bbase[4];
#pragma unroll
    for (int mi = 0; mi < 4; mi++) Abase[mi] = (wave_m + mi * 16 + l15) * 256;
#pragma unroll
    for (int ni = 0; ni < 4; ni++) Bbase[ni] = (wave_n + ni * 16 + l15) * 128;
    const int pA = (quad * 2) ^ l15;          // slot of A lo-granule for kt=0
    const int pB = (quad * 2) ^ (l15 & 7);    // slot of B lo-granule

    float bestv[4][4];
    int   bestc[4][4];
#pragma unroll
    for (int mi = 0; mi < 4; mi++)
#pragma unroll
        for (int reg = 0; reg < 4; reg++) { bestv[mi][reg] = -1e30f; bestc[mi][reg] = 0; }

    f32x4 acc[4][4];
#pragma unroll
    for (int i = 0; i < 4; i++)
#pragma unroll
        for (int jj = 0; jj < 4; jj++) acc[i][jj] = (f32x4){0.f, 0.f, 0.f, 0.f};

#define COMPUTE(BS, KT) do {                                                           \
        v8i af[4];                                                                     \
        _Pragma("unroll")                                                              \
        for (int mi = 0; mi < 4; mi++) {                                               \
            const int _lo = Abase[mi] + ((pA ^ ((KT) << 3)) << 4);                     \
            v4i _x = *(const v4i*)&Asw[_lo];                                           \
            v4i _y = *(const v4i*)&Asw[_lo ^ 16];                                      \
            af[mi] = __builtin_shufflevector(_x, _y, 0, 1, 2, 3, 4, 5, 6, 7);          \
        }                                                                              \
        _Pragma("unroll")                                                              \
        for (int ni = 0; ni < 4; ni++) {                                               \
            const int _lo = Bbase[ni] + (pB << 4);                                     \
            v4i _x = *(const v4i*)&BS[_lo];                                            \
            v4i _y = *(const v4i*)&BS[_lo ^ 16];                                       \
            v8i bv = __builtin_shufflevector(_x, _y, 0, 1, 2, 3, 4, 5, 6, 7);          \
            _Pragma("unroll")                                                          \
            for (int mi = 0; mi < 4; mi++)                                             \
                acc[mi][ni] = MFMA_FP8(af[mi], bv, acc[mi][ni]);                       \
        }                                                                              \
    } while (0)

    PREFB(0, Bs0);   // prologue (A issues already in flight)

#pragma unroll 1
    for (int p = 0; p < NCHUNK; ++p) {
        __syncthreads();                 // A + B tile 2p ready; Bs1 free
        PREFB(2 * p + 1, Bs1);
        COMPUTE(Bs0, 0);                 // chunk p, k 0..127
        __syncthreads();                 // B tile 2p+1 ready; Bs0 free
        if (p < NCHUNK - 1) PREFB(2 * p + 2, Bs0);
        COMPUTE(Bs1, 1);                 // chunk p, k 128..255

        // chunk p complete: fold into running best, reset acc
        const int col0 = nbase + p * BN + wave_n + l15;
#pragma unroll
        for (int mi = 0; mi < 4; mi++) {
#pragma unroll
            for (int reg = 0; reg < 4; reg++) {
#pragma unroll
                for (int ni = 0; ni < 4; ni++) {
                    float v = acc[mi][ni][reg];
                    int   c = col0 + ni * 16;
                    if (v > bestv[mi][reg]) { bestv[mi][reg] = v; bestc[mi][reg] = c; }
                }
                acc[mi][0][reg] = 0.f; acc[mi][1][reg] = 0.f;
                acc[mi][2][reg] = 0.f; acc[mi][3][reg] = 0.f;
            }
        }
    }

    // Epilogue (once per block): pack, 16-lane reduce, one atomic per slot
#pragma unroll
    for (int mi = 0; mi < 4; mi++) {
#pragma unroll
        for (int reg = 0; reg < 4; reg++) {
            unsigned long long key =
                ((unsigned long long)f32_ordered(bestv[mi][reg]) << 32) |
                (unsigned long long)(0xFFFFFFFFu - (unsigned)bestc[mi][reg]);   // ~col: ties -> smaller col
#pragma unroll
            for (int m = 1; m < 16; m <<= 1) {
                unsigned long long o = __shfl_xor(key, m, 16);
                if (o > key) key = o;
            }
            if (l15 == mi * 4 + reg) {
                int row = blk_m + wave_m + mi * 16 + quad * 4 + reg;
                atomicMax(&amax[row], key);
            }
        }
    }
}

// ---------- logits + online logsumexp - diag + final reduce ----------
// Gather reads the ORIGINAL fp32 queue (full precision), converts to bf16
// fragments in-register. One block (8 waves) per 16 rows; waves split the
// 128 column-tiles 16 each; merged through LDS; one atomicAdd per block.
__global__ __launch_bounds__(512) void logits_ce_kernel(const unsigned long long* __restrict__ amax,
                                                        const float* __restrict__ queue_f32,
                                                        const unsigned short* __restrict__ preds_bf,
                                                        float* __restrict__ out) {
    const int gw   = blockIdx.x;        // 0..255 (16-row group)
    const int tid  = threadIdx.x;
    const int wave = tid >> 6;          // 0..7
    const int lane = tid & 63;
    const int l15  = lane & 15;
    const int quad = lane >> 4;
    const int h    = gw >> 7;           // 0: ab, 1: ba
    const int rowbase = gw * 16;
    const unsigned short* Bbase = preds_bf + (size_t)((1 - h) * HALF) * D_K;

    __shared__ float sm[8][16], sl[8][16], sd[8][16];

    // inline gather from fp32 queue: this lane's A-row = queue[argmax(rowbase+l15)]
    unsigned idx = 0xFFFFFFFFu - (unsigned)(amax[rowbase + l15] & 0xFFFFFFFFull);
    const float* arow = queue_f32 + (size_t)idx * D_K;
    bf16x8 a[8];
#pragma unroll
    for (int kc = 0; kc < 8; kc++) {
        float4 f0 = *(const float4*)(arow + kc * 32 + quad * 8);
        float4 f1 = *(const float4*)(arow + kc * 32 + quad * 8 + 4);
        u16x8 t;
        t[0] = f2bf_rn(f0.x); t[1] = f2bf_rn(f0.y); t[2] = f2bf_rn(f0.z); t[3] = f2bf_rn(f0.w);
        t[4] = f2bf_rn(f1.x); t[5] = f2bf_rn(f1.y); t[6] = f2bf_rn(f1.z); t[7] = f2bf_rn(f1.w);
        a[kc] = *(const bf16x8*)&t;
    }

    float m_run[4], l_run[4], diag[4];
#pragma unroll
    for (int r = 0; r < 4; r++) { m_run[r] = -1e30f; l_run[r] = 0.f; diag[r] = -1e30f; }

    const int tdiag = gw & 127;
    for (int tt = 0; tt < 16; tt++) {
        const int t = wave * 16 + tt;
        f32x4 acc = (f32x4){0.f, 0.f, 0.f, 0.f};
#pragma unroll
        for (int kc = 0; kc < 8; kc++) {
            bf16x8 b = *(const bf16x8*)&Bbase[(size_t)(t * 16 + l15) * D_K + kc * 32 + quad * 8];
            acc = __builtin_amdgcn_mfma_f32_16x16x32_bf16(a[kc], b, acc, 0, 0, 0);
        }
#pragma unroll
        for (int reg = 0; reg < 4; reg++) {
            float v = acc[reg] * 10.0f;              // 1/TEMPERATURE
            if (t == tdiag && l15 == quad * 4 + reg) diag[reg] = v;
            float nm = fmaxf(m_run[reg], v);
            l_run[reg] = l_run[reg] * __expf(m_run[reg] - nm) + __expf(v - nm);
            m_run[reg] = nm;
        }
    }
    // 16-lane merge within the wave
#pragma unroll
    for (int reg = 0; reg < 4; reg++) {
#pragma unroll
        for (int m = 1; m < 16; m <<= 1) {
            float om = __shfl_xor(m_run[reg], m, 16);
            float ol = __shfl_xor(l_run[reg], m, 16);
            float od = __shfl_xor(diag[reg], m, 16);
            float nm = fmaxf(m_run[reg], om);
            l_run[reg] = l_run[reg] * __expf(m_run[reg] - nm) + ol * __expf(om - nm);
            m_run[reg] = nm;
            diag[reg] = fmaxf(diag[reg], od);
        }
        if (l15 == 0) {
            sm[wave][quad * 4 + reg] = m_run[reg];
            sl[wave][quad * 4 + reg] = l_run[reg];
            sd[wave][quad * 4 + reg] = diag[reg];
        }
    }
    __syncthreads();
    // cross-wave merge + block-local reduce + single atomic into out
    if (tid < 16) {
        float M = -1e30f, L = 0.f, Dg = -1e30f;
#pragma unroll
        for (int w = 0; w < 8; w++) {
            float mw = sm[w][tid], lw = sl[w][tid], dw = sd[w][tid];
            float nM = fmaxf(M, mw);
            L = L * __expf(M - nM) + lw * __expf(mw - nM);
            M = nM;
            Dg = fmaxf(Dg, dw);
        }
        float rl = (M + __logf(L)) - Dg;
#pragma unroll
        for (int m = 1; m < 16; m <<= 1) rl += __shfl_xor(rl, m, 16);
        if (tid == 0) atomicAdd(out, rl * (1.0f / (float)B_ROWS));
    }
}

extern "C" void kernel_launch(void* const* d_in, const int* in_sizes, int n_in,
                              void* d_out, int out_size, void* d_ws, size_t ws_size,
                              hipStream_t stream) {
    const float* emb   = (const float*)d_in[0];
    const float* preds = (const float*)d_in[1];
    const float* queue = (const float*)d_in[2];

    char* w = (char*)d_ws;
    unsigned long long* amax  = (unsigned long long*)w;                     // 32 KB
    unsigned char*  emb8      = (unsigned char*)(w + (1u << 20));           // 1 MB
    unsigned short* preds_bf  = (unsigned short*)(w + (2u << 20));          // 2 MB
    unsigned char*  queue8    = (unsigned char*)(w + (4u << 20));           // 16 MB

    prep_kernel<<<dim3((EMB4 + PRED4 + QUE4) / 256), 256, 0, stream>>>(
        emb, preds, queue, emb8, preds_bf, queue8, amax, (float*)d_out);
    sim_argmax_kernel<<<dim3((B_ROWS / BM) * (Q_ROWS / (BN * NCHUNK))), 256, 0, stream>>>(
        emb8, queue8, amax);
    logits_ce_kernel<<<dim3(B_ROWS / 16), 512, 0, stream>>>(
        amax, queue, preds_bf, (float*)d_out);
}